// Round 3
// baseline (524.924 us; speedup 1.0000x reference)
//
#include <hip/hip_runtime.h>
#include <hip/hip_bf16.h>

#define NPTS 1024
#define EPSF 1e-7f

// ---- ws layout (fp32 elements) ----
// A0 [0,32768)      : feat@l0_fc0_w[0:40] + b0   (per point i)
// B0 [32768,65536)  : feat@l0_fc0_w[40:80]       (per point j)
// A1 [65536,98304)  : feat@l0_fc1_w[0:40] + b1
// B1 [98304,131072) : feat@l0_fc1_w[40:80]
#define OFF_W0P  131072  // l0_fc0_w rows 80..83 (4x32)
#define OFF_W1P  131200  // l0_fc1_w rows 80..83
#define OFF_L0W2 131328  // 32x32
#define OFF_L0B2 132352  // 32
#define OFF_L1W1 132384  // 32x32
#define OFF_L1B1 133408
#define OFF_L1W2 133440
#define OFF_L1B2 134464
#define OFF_L2W0 134496  // 32x16
#define OFF_L2B0 135008
#define OFF_L2W1 135024  // 32x16
#define OFF_L2B1 135536
#define OFF_L2W2 135552  // 16x16
#define OFF_L2B2 135808
#define OFF_FW   135824  // 16x66
#define OFF_FB   136880  // 66
// total 136946 floats = 547,784 bytes of ws

typedef const float* fp;

// blocks 0..1023: per-point A/B partials.  blocks 1024+: weight staging into ws.
__global__ __launch_bounds__(128) void ppf_pre(
    fp feat, fp w0, fp b0, fp w1, fp b1,
    fp l0w2, fp l0b2, fp l1w1, fp l1b1, fp l1w2, fp l1b2,
    fp l2w0, fp l2b0, fp l2w1, fp l2b1, fp l2w2, fp l2b2,
    fp fw, fp fb, float* __restrict__ ws)
{
    if (blockIdx.x < 1024) {
        __shared__ float f[40];
        int p = blockIdx.x;
        int t = threadIdx.x;
        if (t < 40) f[t] = feat[p * 40 + t];
        __syncthreads();
        int g = t >> 5;          // 0:A0 1:B0 2:A1 3:B1
        int c = t & 31;
        fp W = (g < 2) ? w0 : w1;
        int rowoff = (g & 1) ? 40 : 0;
        float acc = 0.f;
        if (!(g & 1)) acc = (g < 2) ? b0[c] : b1[c];
        #pragma unroll
        for (int k = 0; k < 40; ++k)
            acc += f[k] * W[(rowoff + k) * 32 + c];
        ws[g * 32768 + p * 32 + c] = acc;
    } else {
        int t = (blockIdx.x - 1024) * 128 + threadIdx.x;
        if (t < 128)            { ws[OFF_W0P + t] = w0[80*32 + t]; return; }
        t -= 128;
        if (t < 128)            { ws[OFF_W1P + t] = w1[80*32 + t]; return; }
        t -= 128;
        if (t < 1024)           { ws[OFF_L0W2 + t] = l0w2[t]; return; }
        t -= 1024;
        if (t < 32)             { ws[OFF_L0B2 + t] = l0b2[t]; return; }
        t -= 32;
        if (t < 1024)           { ws[OFF_L1W1 + t] = l1w1[t]; return; }
        t -= 1024;
        if (t < 32)             { ws[OFF_L1B1 + t] = l1b1[t]; return; }
        t -= 32;
        if (t < 1024)           { ws[OFF_L1W2 + t] = l1w2[t]; return; }
        t -= 1024;
        if (t < 32)             { ws[OFF_L1B2 + t] = l1b2[t]; return; }
        t -= 32;
        if (t < 512)            { ws[OFF_L2W0 + t] = l2w0[t]; return; }
        t -= 512;
        if (t < 16)             { ws[OFF_L2B0 + t] = l2b0[t]; return; }
        t -= 16;
        if (t < 512)            { ws[OFF_L2W1 + t] = l2w1[t]; return; }
        t -= 512;
        if (t < 16)             { ws[OFF_L2B1 + t] = l2b1[t]; return; }
        t -= 16;
        if (t < 256)            { ws[OFF_L2W2 + t] = l2w2[t]; return; }
        t -= 256;
        if (t < 16)             { ws[OFF_L2B2 + t] = l2b2[t]; return; }
        t -= 16;
        if (t < 1056)           { ws[OFF_FW + t] = fw[t]; return; }
        t -= 1056;
        if (t < 66)             { ws[OFF_FB + t] = fb[t]; return; }
    }
}

__global__ __launch_bounds__(256) void ppf_main(
    fp pc, fp nrm, fp dist, const float* __restrict__ ws,
    float* __restrict__ out)
{
    const int i = blockIdx.x >> 2;
    const int j = ((blockIdx.x & 3) << 8) | threadIdx.x;

    // ---- PPF features ----
    const float d  = dist[i * NPTS + j];
    const float inv = 1.f / (d + EPSF);
    const float pix = pc[i*3+0], piy = pc[i*3+1], piz = pc[i*3+2];
    const float pjx = pc[j*3+0], pjy = pc[j*3+1], pjz = pc[j*3+2];
    const float xn0 = (pix - pjx) * inv, xn1 = (piy - pjy) * inv, xn2 = (piz - pjz) * inv;
    const float ni0 = nrm[i*3+0], ni1 = nrm[i*3+1], ni2 = nrm[i*3+2];
    const float nj0 = nrm[j*3+0], nj1 = nrm[j*3+1], nj2 = nrm[j*3+2];
    const float p0 = ni0*xn0 + ni1*xn1 + ni2*xn2;
    const float p1 = nj0*xn0 + nj1*xn1 + nj2*xn2;
    const float p2 = ni0*nj0 + ni1*nj1 + ni2*nj2;
    const float p3 = d;

    const float* A0 = ws + i * 32;
    const float* B0 = ws + 32768 + j * 32;
    const float* A1 = ws + 65536 + i * 32;
    const float* B1 = ws + 98304 + j * 32;
    const float* w0p = ws + OFF_W0P;
    const float* w1p = ws + OFF_W1P;

    // ---- layer 0 ----
    float x1[32], h[32];
    #pragma unroll
    for (int c = 0; c < 32; ++c) {
        float u0 = A0[c] + B0[c] + p0*w0p[c] + p1*w0p[32+c] + p2*w0p[64+c] + p3*w0p[96+c];
        float u1 = A1[c] + B1[c] + p0*w1p[c] + p1*w1p[32+c] + p2*w1p[64+c] + p3*w1p[96+c];
        h[c]  = fmaxf(u1, 0.f);
        x1[c] = ws[OFF_L0B2 + c] + u0;
    }
    {
        const float* W = ws + OFF_L0W2;
        #pragma unroll 4
        for (int k = 0; k < 32; ++k)
            #pragma unroll
            for (int c = 0; c < 32; ++c)
                x1[c] += h[k] * W[k*32 + c];
    }

    // ---- layer 1 ----
    float x2[32];
    #pragma unroll
    for (int c = 0; c < 32; ++c) h[c] = ws[OFF_L1B1 + c];
    {
        const float* W = ws + OFF_L1W1;
        #pragma unroll 4
        for (int k = 0; k < 32; ++k)
            #pragma unroll
            for (int c = 0; c < 32; ++c)
                h[c] += x1[k] * W[k*32 + c];
    }
    #pragma unroll
    for (int c = 0; c < 32; ++c) { h[c] = fmaxf(h[c], 0.f); x2[c] = ws[OFF_L1B2 + c] + x1[c]; }
    {
        const float* W = ws + OFF_L1W2;
        #pragma unroll 4
        for (int k = 0; k < 32; ++k)
            #pragma unroll
            for (int c = 0; c < 32; ++c)
                x2[c] += h[k] * W[k*32 + c];
    }

    // ---- layer 2 ----
    float r[16], h3[16];
    #pragma unroll
    for (int c = 0; c < 16; ++c) { r[c] = ws[OFF_L2B0 + c]; h3[c] = ws[OFF_L2B1 + c]; }
    {
        const float* W0 = ws + OFF_L2W0;
        const float* W1 = ws + OFF_L2W1;
        #pragma unroll 4
        for (int k = 0; k < 32; ++k)
            #pragma unroll
            for (int c = 0; c < 16; ++c) {
                r[c]  += x2[k] * W0[k*16 + c];
                h3[c] += x2[k] * W1[k*16 + c];
            }
    }
    float x3[16];
    #pragma unroll
    for (int c = 0; c < 16; ++c) { h3[c] = fmaxf(h3[c], 0.f); x3[c] = ws[OFF_L2B2 + c] + r[c]; }
    {
        const float* W = ws + OFF_L2W2;
        #pragma unroll 4
        for (int k = 0; k < 16; ++k)
            #pragma unroll
            for (int c = 0; c < 16; ++c)
                x3[c] += h3[k] * W[k*16 + c];
    }

    // ---- final 16 -> 66 ----
    float o[66];
    #pragma unroll
    for (int c = 0; c < 66; ++c) o[c] = ws[OFF_FB + c];
    {
        const float* W = ws + OFF_FW;
        #pragma unroll 2
        for (int k = 0; k < 16; ++k)
            #pragma unroll
            for (int c = 0; c < 66; ++c)
                o[c] += x3[k] * W[k*66 + c];
    }

    // ---- store 66 fp32 = 33 float2, 8B aligned (66*4 = 264 = 8*33) ----
    float2* op = (float2*)(out + (size_t)(i * NPTS + j) * 66);
    #pragma unroll
    for (int c = 0; c < 33; ++c)
        op[c] = make_float2(o[2*c], o[2*c + 1]);
}

extern "C" void kernel_launch(void* const* d_in, const int* in_sizes, int n_in,
                              void* d_out, int out_size, void* d_ws, size_t ws_size,
                              hipStream_t stream) {
    (void)in_sizes; (void)n_in; (void)out_size; (void)ws_size;
    fp pc   = (fp)d_in[0];
    fp nrm  = (fp)d_in[1];
    fp dist = (fp)d_in[2];
    fp feat = (fp)d_in[3];
    fp w0   = (fp)d_in[4];   fp b0   = (fp)d_in[5];
    fp w1   = (fp)d_in[6];   fp b1   = (fp)d_in[7];
    fp l0w2 = (fp)d_in[8];   fp l0b2 = (fp)d_in[9];
    fp l1w1 = (fp)d_in[10];  fp l1b1 = (fp)d_in[11];
    fp l1w2 = (fp)d_in[12];  fp l1b2 = (fp)d_in[13];
    fp l2w0 = (fp)d_in[14];  fp l2b0 = (fp)d_in[15];
    fp l2w1 = (fp)d_in[16];  fp l2b1 = (fp)d_in[17];
    fp l2w2 = (fp)d_in[18];  fp l2b2 = (fp)d_in[19];
    fp fw   = (fp)d_in[20];  fp fb   = (fp)d_in[21];
    float* ws = (float*)d_ws;
    float* out = (float*)d_out;

    // 1024 A/B blocks + 48 staging blocks (6144 threads >= 5874 elems)
    ppf_pre<<<1072, 128, 0, stream>>>(feat, w0, b0, w1, b1,
        l0w2, l0b2, l1w1, l1b1, l1w2, l1b2,
        l2w0, l2b0, l2w1, l2b1, l2w2, l2b2, fw, fb, ws);

    ppf_main<<<4096, 256, 0, stream>>>(pc, nrm, dist, ws, out);
}

// Round 4
// 432.345 us; speedup vs baseline: 1.2141x; 1.2141x over previous
//
#include <hip/hip_runtime.h>
#include <hip/hip_bf16.h>

#define NPTS 1024
#define EPSF 1e-7f

typedef const float* fp;
typedef __attribute__((ext_vector_type(8))) short short8;
typedef __attribute__((ext_vector_type(4))) float float4v;

// ---- ws layout (fp32 / dword elements) ----
// A0 [0,32768)      : feat@l0_fc0_w[0:40] + b0   (per point i)
// B0 [32768,65536)  : feat@l0_fc0_w[40:80]       (per point j)
// A1 [65536,98304)  : feat@l0_fc1_w[0:40] + b1
// B1 [98304,131072) : feat@l0_fc1_w[40:80]
#define OFF_B0   32768
#define OFF_A1   65536
#define OFF_B1   98304
#define OFF_FRAG 131072   // 14 frags * 256 dwords (64 lanes * 4 dwords = short8/lane)
#define OFF_W0PT 134656   // 128: W0p transposed [k][t] (ppf rows 80..83 of l0_fc0_w)
#define OFF_W1PT 134784   // 128
// total 134912 dwords = 539,648 B

static __device__ __forceinline__ short f2bf(float x) {
    __hip_bfloat16 h = __float2bfloat16(x);
    short s; __builtin_memcpy(&s, &h, 2); return s;
}
static __device__ __forceinline__ void lds_fence() {
    __asm__ volatile("s_waitcnt lgkmcnt(0)" ::: "memory");
}

// blocks 0..1023   : per-point A/B partials
// blocks 1024..1037: B-fragment staging (bf16, MFMA B-layout) for the 10 weight mats
// blocks 1038,1039 : W0p/W1p transposed ([k][t]) for the ppf K=4 GEMM
__global__ __launch_bounds__(128) void ppf_pre(
    fp feat, fp w0, fp b0, fp w1, fp b1,
    fp l0w2, fp l1w1, fp l1w2, fp l2w0, fp l2w1, fp l2w2, fp fw,
    float* __restrict__ ws)
{
    const int bid = blockIdx.x;
    const int t = threadIdx.x;
    if (bid < 1024) {
        __shared__ float f[40];
        int p = bid;
        if (t < 40) f[t] = feat[p * 40 + t];
        __syncthreads();
        int g = t >> 5;          // 0:A0 1:B0 2:A1 3:B1
        int c = t & 31;
        fp W = (g < 2) ? w0 : w1;
        int rowoff = (g & 1) ? 40 : 0;
        float acc = 0.f;
        if (!(g & 1)) acc = (g < 2) ? b0[c] : b1[c];
        #pragma unroll
        for (int k = 0; k < 40; ++k)
            acc += f[k] * W[(rowoff + k) * 32 + c];
        ws[g * 32768 + p * 32 + c] = acc;
    } else if (bid < 1038) {
        // stage B-fragment for frag id ff: lane l holds B[k=(l>>4)*8+j][n=n0+(l&15)], j=0..7
        int ff = bid - 1024;
        if (t >= 64) return;
        const float* src; int Kr, Nw, n0;
        switch (ff) {
            case 0:  src = l0w2; Kr = 32; Nw = 32; n0 = 0;  break;
            case 1:  src = l0w2; Kr = 32; Nw = 32; n0 = 16; break;
            case 2:  src = l1w1; Kr = 32; Nw = 32; n0 = 0;  break;
            case 3:  src = l1w1; Kr = 32; Nw = 32; n0 = 16; break;
            case 4:  src = l1w2; Kr = 32; Nw = 32; n0 = 0;  break;
            case 5:  src = l1w2; Kr = 32; Nw = 32; n0 = 16; break;
            case 6:  src = l2w0; Kr = 32; Nw = 16; n0 = 0;  break;
            case 7:  src = l2w1; Kr = 32; Nw = 16; n0 = 0;  break;
            case 8:  src = l2w2; Kr = 16; Nw = 16; n0 = 0;  break;
            default: src = fw;   Kr = 16; Nw = 66; n0 = (ff - 9) * 16; break;
        }
        int q = t >> 4;
        int n = n0 + (t & 15);
        unsigned dw[4];
        #pragma unroll
        for (int w = 0; w < 4; ++w) {
            unsigned short e[2];
            #pragma unroll
            for (int v = 0; v < 2; ++v) {
                int k = q * 8 + w * 2 + v;
                float val = (k < Kr && n < Nw) ? src[k * Nw + n] : 0.f;
                short s = f2bf(val);
                __builtin_memcpy(&e[v], &s, 2);
            }
            dw[w] = (unsigned)e[0] | ((unsigned)e[1] << 16);
        }
        unsigned* dst = (unsigned*)ws + OFF_FRAG + ff * 256 + t * 4;
        #pragma unroll
        for (int w = 0; w < 4; ++w) dst[w] = dw[w];
    } else if (bid == 1038) {
        // W0PT[k][tt] = w0[(80+tt)*32 + k];  index k*4+tt == t
        ws[OFF_W0PT + t] = w0[(80 + (t & 3)) * 32 + (t >> 2)];
    } else {
        ws[OFF_W1PT + t] = w1[(80 + (t & 3)) * 32 + (t >> 2)];
    }
}

static __device__ __forceinline__ float4v mfma16(short8 a, short8 b, float4v c) {
    return __builtin_amdgcn_mfma_f32_16x16x32_bf16(a, b, c, 0, 0, 0);
}

// 4096 blocks x 256 threads. Block: i = bid>>2, j-range = (bid&3)*256.
// Wave wv handles j-subrange wv*64, 4 tiles of 16 pairs.
__global__ __launch_bounds__(256) void ppf_main(
    fp pc, fp nrm, fp dist,
    fp l0b2, fp l1b1, fp l1b2, fp l2b0, fp l2b1, fp l2b2, fp fb,
    const float* __restrict__ ws, float* __restrict__ out)
{
    __shared__ __align__(16) float lds[4 * 1152];   // per wave: xt[16][36] + ht[16][36]
    const int tid  = threadIdx.x;
    const int wv   = tid >> 6;
    const int lane = tid & 63;
    const int q    = lane >> 4;
    const int ml   = lane & 15;
    const int kb   = q * 8;
    float* xt = &lds[wv * 1152];
    float* ht = xt + 576;

    const int i    = blockIdx.x >> 2;
    const int jblk = ((blockIdx.x & 3) << 8) + (wv << 6);

    // ---- weight fragments, resident in VGPRs for the whole kernel ----
    const short8* fragp = (const short8*)(ws + OFF_FRAG);
    const short8 fg_l0w2_0 = fragp[0 * 64 + lane], fg_l0w2_1 = fragp[1 * 64 + lane];
    const short8 fg_l1w1_0 = fragp[2 * 64 + lane], fg_l1w1_1 = fragp[3 * 64 + lane];
    const short8 fg_l1w2_0 = fragp[4 * 64 + lane], fg_l1w2_1 = fragp[5 * 64 + lane];
    const short8 fg_l2w0   = fragp[6 * 64 + lane];
    const short8 fg_l2w1   = fragp[7 * 64 + lane];
    const short8 fg_l2w2   = fragp[8 * 64 + lane];
    const short8 fg_fw0 = fragp[9 * 64 + lane],  fg_fw1 = fragp[10 * 64 + lane];
    const short8 fg_fw2 = fragp[11 * 64 + lane], fg_fw3 = fragp[12 * 64 + lane];
    const short8 fg_fw4 = fragp[13 * 64 + lane];

    // ---- per-lane invariant slices ----
    const float4v* a0p = (const float4v*)(ws + i * 32 + kb);
    const float4v a0lo = a0p[0], a0hi = a0p[1];
    const float4v* a1p = (const float4v*)(ws + OFF_A1 + i * 32 + kb);
    const float4v a1lo = a1p[0], a1hi = a1p[1];
    const float4v* b2p = (const float4v*)(l0b2 + kb);
    const float4v b2lo = b2p[0], b2hi = b2p[1];
    float4v w0t[8], w1t[8];
    {
        const float4v* w0ptp = (const float4v*)(ws + OFF_W0PT + kb * 4);
        const float4v* w1ptp = (const float4v*)(ws + OFF_W1PT + kb * 4);
        #pragma unroll
        for (int jj = 0; jj < 8; ++jj) { w0t[jj] = w0ptp[jj]; w1t[jj] = w1ptp[jj]; }
    }
    const float bl1b1_0 = l1b1[ml], bl1b1_1 = l1b1[16 + ml];
    const float bl1b2_0 = l1b2[ml], bl1b2_1 = l1b2[16 + ml];
    const float bl2b0 = l2b0[ml], bl2b1 = l2b1[ml], bl2b2 = l2b2[ml];
    float bfb[5];
    #pragma unroll
    for (int nt = 0; nt < 5; ++nt) { int c = nt * 16 + ml; bfb[nt] = (c < 66) ? fb[c] : 0.f; }

    const float pix = pc[i * 3], piy = pc[i * 3 + 1], piz = pc[i * 3 + 2];
    const float nix = nrm[i * 3], niy = nrm[i * 3 + 1], niz = nrm[i * 3 + 2];
    const float4v z4 = {0.f, 0.f, 0.f, 0.f};

    for (int tt = 0; tt < 4; ++tt) {
        const int j0 = jblk + tt * 16;
        const int jm = j0 + ml;

        // ---- ppf (lane owns pair m=ml; redundant across quads) ----
        const float d   = dist[i * NPTS + jm];
        const float inv = 1.f / (d + EPSF);
        const float dx = (pix - pc[jm * 3]) * inv;
        const float dy = (piy - pc[jm * 3 + 1]) * inv;
        const float dz = (piz - pc[jm * 3 + 2]) * inv;
        const float njx = nrm[jm * 3], njy = nrm[jm * 3 + 1], njz = nrm[jm * 3 + 2];
        const float p0 = nix * dx + niy * dy + niz * dz;
        const float p1 = njx * dx + njy * dy + njz * dz;
        const float p2 = nix * njx + niy * njy + niz * njz;
        const float p3 = d;

        const float4v* b0p = (const float4v*)(ws + OFF_B0 + jm * 32 + kb);
        const float4v b0lo = b0p[0], b0hi = b0p[1];
        const float4v* b1p = (const float4v*)(ws + OFF_B1 + jm * 32 + kb);
        const float4v b1lo = b1p[0], b1hi = b1p[1];

        // ---- layer0 pre-acts in A-layout: u0 (residual path), u1 (relu path) ----
        float u0[8], u1[8];
        #pragma unroll
        for (int jj = 0; jj < 8; ++jj) {
            const float4v wa = w0t[jj], wb = w1t[jj];
            const float a0v = (jj < 4) ? a0lo[jj] : a0hi[jj - 4];
            const float a1v = (jj < 4) ? a1lo[jj] : a1hi[jj - 4];
            const float b0v = (jj < 4) ? b0lo[jj] : b0hi[jj - 4];
            const float b1v = (jj < 4) ? b1lo[jj] : b1hi[jj - 4];
            u0[jj] = a0v + b0v + p0 * wa.x + p1 * wa.y + p2 * wa.z + p3 * wa.w;
            u1[jj] = a1v + b1v + p0 * wb.x + p1 * wb.y + p2 * wb.z + p3 * wb.w;
        }

        // ---- L0 MFMA: D = relu(u1) @ l0w2 ----
        short8 ha;
        #pragma unroll
        for (int jj = 0; jj < 8; ++jj) ha[jj] = f2bf(fmaxf(u1[jj], 0.f));
        float4v d0 = mfma16(ha, fg_l0w2_0, z4);
        float4v d1 = mfma16(ha, fg_l0w2_1, z4);

        // D -> LDS (D-layout), read back A-layout, combine x1 = D + u0 + b2
        #pragma unroll
        for (int rr = 0; rr < 4; ++rr) {
            xt[(q * 4 + rr) * 36 + ml]      = d0[rr];
            xt[(q * 4 + rr) * 36 + 16 + ml] = d1[rr];
        }
        lds_fence();
        float4v xalo = *(const float4v*)&xt[ml * 36 + kb];
        float4v xahi = *(const float4v*)&xt[ml * 36 + kb + 4];
        float x1a[8];
        #pragma unroll
        for (int jj = 0; jj < 8; ++jj) {
            const float dv = (jj < 4) ? xalo[jj] : xahi[jj - 4];
            const float bv = (jj < 4) ? b2lo[jj] : b2hi[jj - 4];
            x1a[jj] = dv + u0[jj] + bv;
        }
        // write x1 tile (plain [m][c]) for L1 residual reads
        float4v x1w0 = {x1a[0], x1a[1], x1a[2], x1a[3]};
        float4v x1w1 = {x1a[4], x1a[5], x1a[6], x1a[7]};
        *(float4v*)&xt[ml * 36 + kb]     = x1w0;
        *(float4v*)&xt[ml * 36 + kb + 4] = x1w1;
        lds_fence();

        // ---- L1 ----
        short8 x1b;
        #pragma unroll
        for (int jj = 0; jj < 8; ++jj) x1b[jj] = f2bf(x1a[jj]);
        float4v ch0 = {bl1b1_0, bl1b1_0, bl1b1_0, bl1b1_0};
        float4v ch1 = {bl1b1_1, bl1b1_1, bl1b1_1, bl1b1_1};
        float4v dh0 = mfma16(x1b, fg_l1w1_0, ch0);
        float4v dh1 = mfma16(x1b, fg_l1w1_1, ch1);
        #pragma unroll
        for (int rr = 0; rr < 4; ++rr) {
            dh0[rr] = fmaxf(dh0[rr], 0.f);
            dh1[rr] = fmaxf(dh1[rr], 0.f);
            ht[(q * 4 + rr) * 36 + ml]      = dh0[rr];
            ht[(q * 4 + rr) * 36 + 16 + ml] = dh1[rr];
        }
        lds_fence();
        float4v hlo = *(const float4v*)&ht[ml * 36 + kb];
        float4v hhi = *(const float4v*)&ht[ml * 36 + kb + 4];
        short8 h1b;
        #pragma unroll
        for (int jj = 0; jj < 8; ++jj) h1b[jj] = f2bf((jj < 4) ? hlo[jj] : hhi[jj - 4]);
        float4v c20, c21;
        #pragma unroll
        for (int rr = 0; rr < 4; ++rr) {
            c20[rr] = xt[(q * 4 + rr) * 36 + ml]      + bl1b2_0;
            c21[rr] = xt[(q * 4 + rr) * 36 + 16 + ml] + bl1b2_1;
        }
        float4v dx20 = mfma16(h1b, fg_l1w2_0, c20);
        float4v dx21 = mfma16(h1b, fg_l1w2_1, c21);

        // x2 -> A-layout via xt (overwrite x1)
        #pragma unroll
        for (int rr = 0; rr < 4; ++rr) {
            xt[(q * 4 + rr) * 36 + ml]      = dx20[rr];
            xt[(q * 4 + rr) * 36 + 16 + ml] = dx21[rr];
        }
        lds_fence();
        float4v x2lo = *(const float4v*)&xt[ml * 36 + kb];
        float4v x2hi = *(const float4v*)&xt[ml * 36 + kb + 4];
        short8 x2b;
        #pragma unroll
        for (int jj = 0; jj < 8; ++jj) x2b[jj] = f2bf((jj < 4) ? x2lo[jj] : x2hi[jj - 4]);

        // ---- L2 ----
        float4v cr  = {bl2b0, bl2b0, bl2b0, bl2b0};
        float4v dr  = mfma16(x2b, fg_l2w0, cr);          // residual path (16 cols)
        float4v cb  = {bl2b1, bl2b1, bl2b1, bl2b1};
        float4v dh2 = mfma16(x2b, fg_l2w1, cb);
        #pragma unroll
        for (int rr = 0; rr < 4; ++rr) {
            dh2[rr] = fmaxf(dh2[rr], 0.f);
            ht[(q * 4 + rr) * 36 + ml] = dh2[rr];        // cols 0..15 only
        }
        lds_fence();
        float4v h2lo = (q < 2) ? *(const float4v*)&ht[ml * 36 + kb]     : z4;
        float4v h2hi = (q < 2) ? *(const float4v*)&ht[ml * 36 + kb + 4] : z4;
        short8 h2b;
        #pragma unroll
        for (int jj = 0; jj < 8; ++jj) h2b[jj] = f2bf((jj < 4) ? h2lo[jj] : h2hi[jj - 4]);
        float4v c3;
        #pragma unroll
        for (int rr = 0; rr < 4; ++rr) c3[rr] = dr[rr] + bl2b2;
        float4v dx3 = mfma16(h2b, fg_l2w2, c3);          // x3, D-layout, cols 0..15

        // ---- final 16 -> 66 ----
        #pragma unroll
        for (int rr = 0; rr < 4; ++rr) xt[(q * 4 + rr) * 36 + ml] = dx3[rr];
        lds_fence();
        float4v x3lo = (q < 2) ? *(const float4v*)&xt[ml * 36 + kb]     : z4;
        float4v x3hi = (q < 2) ? *(const float4v*)&xt[ml * 36 + kb + 4] : z4;
        short8 x3b;
        #pragma unroll
        for (int jj = 0; jj < 8; ++jj) x3b[jj] = f2bf((jj < 4) ? x3lo[jj] : x3hi[jj - 4]);
        float4v cf0 = {bfb[0], bfb[0], bfb[0], bfb[0]};
        float4v cf1 = {bfb[1], bfb[1], bfb[1], bfb[1]};
        float4v cf2 = {bfb[2], bfb[2], bfb[2], bfb[2]};
        float4v cf3 = {bfb[3], bfb[3], bfb[3], bfb[3]};
        float4v cf4 = {bfb[4], bfb[4], bfb[4], bfb[4]};
        float4v o0 = mfma16(x3b, fg_fw0, cf0);
        float4v o1 = mfma16(x3b, fg_fw1, cf1);
        float4v o2 = mfma16(x3b, fg_fw2, cf2);
        float4v o3 = mfma16(x3b, fg_fw3, cf3);
        float4v o4 = mfma16(x3b, fg_fw4, cf4);

        // ---- store: lane covers rows q*4+rr, cols {ml, 16+ml, 32+ml, 48+ml, 64+ml(<66)} ----
        #pragma unroll
        for (int rr = 0; rr < 4; ++rr) {
            float* orow = out + (size_t)(i * NPTS + j0 + q * 4 + rr) * 66;
            orow[ml]      = o0[rr];
            orow[16 + ml] = o1[rr];
            orow[32 + ml] = o2[rr];
            orow[48 + ml] = o3[rr];
            if (ml < 2) orow[64 + ml] = o4[rr];
        }
    }
}

extern "C" void kernel_launch(void* const* d_in, const int* in_sizes, int n_in,
                              void* d_out, int out_size, void* d_ws, size_t ws_size,
                              hipStream_t stream) {
    (void)in_sizes; (void)n_in; (void)out_size; (void)ws_size;
    fp pc   = (fp)d_in[0];
    fp nrm  = (fp)d_in[1];
    fp dist = (fp)d_in[2];
    fp feat = (fp)d_in[3];
    fp w0   = (fp)d_in[4];   fp b0   = (fp)d_in[5];
    fp w1   = (fp)d_in[6];   fp b1   = (fp)d_in[7];
    fp l0w2 = (fp)d_in[8];   fp l0b2 = (fp)d_in[9];
    fp l1w1 = (fp)d_in[10];  fp l1b1 = (fp)d_in[11];
    fp l1w2 = (fp)d_in[12];  fp l1b2 = (fp)d_in[13];
    fp l2w0 = (fp)d_in[14];  fp l2b0 = (fp)d_in[15];
    fp l2w1 = (fp)d_in[16];  fp l2b1 = (fp)d_in[17];
    fp l2w2 = (fp)d_in[18];  fp l2b2 = (fp)d_in[19];
    fp fw   = (fp)d_in[20];  fp fb   = (fp)d_in[21];
    float* ws  = (float*)d_ws;
    float* out = (float*)d_out;

    ppf_pre<<<1040, 128, 0, stream>>>(feat, w0, b0, w1, b1,
        l0w2, l1w1, l1w2, l2w0, l2w1, l2w2, fw, ws);

    ppf_main<<<4096, 256, 0, stream>>>(pc, nrm, dist,
        l0b2, l1b1, l1b2, l2b0, l2b1, l2b2, fb, ws, out);
}